// Round 4
// baseline (162.195 us; speedup 1.0000x reference)
//
#include <hip/hip_runtime.h>
#include <cstdint>

// B,D,H,W,C = 4,8,16,16,512; R=64; F=256; rows=8192; keys/batch=2048.
// v5: occupancy-first k234: 512 blocks x 256 thr (16 rows/block), LDS exactly
//   80 KB -> 2 independent blocks/CU (cross-block latency hiding, m114).
//   Single-barrier-per-step ring-2: { WAITV(own chunk); SBAR; issue next; MFMA }.
//   Each wave waits its OWN staging loads before the barrier => after the
//   barrier the whole chunk is complete. 16 KB union: qsf/a2f/y1f + LN-red
//   scratch in a phase-dead slice (extra SBAR between red-read and y1f-write).
//   k1: ring-3 2-deep, ONE barrier/step (issue after top barrier).
#define LN_EPS 1e-3f
using u16 = unsigned short;
using u32 = unsigned int;
typedef __attribute__((ext_vector_type(8))) short bh8;   // 8 bf16
typedef __attribute__((ext_vector_type(4))) float f4;    // 4 f32 acc
#define MFMA16(A,B,C) __builtin_amdgcn_mfma_f32_16x16x32_bf16((A),(B),(C),0,0,0)
#define SBAR() __builtin_amdgcn_s_barrier()
#define CFENCE() asm volatile("" ::: "memory")
#define WAITV(N) asm volatile("s_waitcnt vmcnt(" #N ")" ::: "memory")
#define LKBAR() do{ asm volatile("s_waitcnt lgkmcnt(0)" ::: "memory"); \
                    __builtin_amdgcn_s_barrier(); asm volatile("" ::: "memory"); }while(0)

__device__ __forceinline__ u16 bf16r(float f){
    union{float f;u32 u;} c; c.f=f;
    return (u16)((c.u + 0x7fffu + ((c.u>>16)&1u))>>16);
}
__device__ __forceinline__ u32 pk2(float a, float b){
    return (u32)bf16r(a) | ((u32)bf16r(b)<<16);
}
__device__ __forceinline__ void glds16(const void* g, void* l){
    __builtin_amdgcn_global_load_lds(
        (const __attribute__((address_space(1))) u32*)g,
        (__attribute__((address_space(3))) u32*)l, 16, 0, 0);
}

// ---------------- K0: pack weights -> bf16 frag-ordered B panels ----------------
__global__ __launch_bounds__(256) void k0_prep(
    const float* __restrict__ wq, const float* __restrict__ wk,
    const float* __restrict__ wv, const float* __restrict__ wm,
    u16* __restrict__ wqkv_p, u16* __restrict__ wm_p)
{
    const int t = threadIdx.x;
    const int c = t & 15, qn = t >> 4;
    const int quad = qn & 3, ntl = qn >> 2;   // ntl 0..3
    const int blk = blockIdx.x;
    if (blk < 32){
        const int s = blk >> 1, hh = blk & 1;
        const int krow = s*32 + quad*8;
        u16* dst = wqkv_p + (size_t)s*20480;
        #pragma unroll
        for (int i=0;i<5;++i){
            const int nt = hh*20 + i*4 + ntl;
            const int n = nt*16 + c;
            const float* src; int ldw;
            if (n < 64){ src = wq + (size_t)krow*64 + n; ldw = 64; }
            else if (n < 128){ src = wk + (size_t)krow*64 + (n-64); ldw = 64; }
            else { src = wv + (size_t)krow*512 + (n-128); ldw = 512; }
            float v[8];
            #pragma unroll
            for (int j=0;j<8;++j) v[j] = src[(size_t)j*ldw];
            uint4 o; o.x=pk2(v[0],v[1]); o.y=pk2(v[2],v[3]); o.z=pk2(v[4],v[5]); o.w=pk2(v[6],v[7]);
            *(uint4*)&dst[((nt*4+quad)*16 + c)*8] = o;
        }
    } else {
        const int bb = blk - 32;
        const int s = bb >> 1, hh = bb & 1;
        const int krow = s*32 + quad*8;
        u16* dst = wm_p + (size_t)s*16384;
        #pragma unroll
        for (int i=0;i<4;++i){
            const int nt = hh*16 + i*4 + ntl;
            const int n = nt*16 + c;
            const float* src = wm + (size_t)krow*512 + n;
            float v[8];
            #pragma unroll
            for (int j=0;j<8;++j) v[j] = src[(size_t)j*512];
            uint4 o; o.x=pk2(v[0],v[1]); o.y=pk2(v[2],v[3]); o.z=pk2(v[4],v[5]); o.w=pk2(v[6],v[7]);
            *(uint4*)&dst[((nt*4+quad)*16 + c)*8] = o;
        }
    }
}

// ---------------- K1: fused QKV projection ----------------
// 256 blocks x 512 thr; 32 rows/block; N=640 (Q64|K64|V512); K=512 in 16 steps.
// ring-3, 2 chunks in flight, ONE barrier per step.
__global__ __launch_bounds__(512) void k1_qkv(
    const float* __restrict__ x, const float* __restrict__ bq, const float* __restrict__ bk,
    const u16* __restrict__ wqkv_p,
    u16* __restrict__ Qb, u16* __restrict__ Kb, u16* __restrict__ Vb)
{
    __shared__ u16 Asf[16384];      // 32 KB: 2 rg-tiles x 16 s x 512 (A frags)
    __shared__ u16 Bs[3][20480];    // 3 x 40 KB ring
    const int t = threadIdx.x, w = t>>6, lane = t&63, quad = (lane>>4)&3, c = lane&15;
    const int rg = w>>2, cg = w&3;
    const int rowbase = blockIdx.x << 5;

    // prologue: chunks 0,1 in flight (overlap with A-staging x loads)
    #pragma unroll
    for (int i=0;i<5;++i)
        glds16((const char*)wqkv_p + (size_t)w*5120 + i*1024 + lane*16,
               (char*)Bs[0] + w*5120 + i*1024);
    #pragma unroll
    for (int i=0;i<5;++i)
        glds16((const char*)wqkv_p + 40960 + (size_t)w*5120 + i*1024 + lane*16,
               (char*)Bs[1] + w*5120 + i*1024);
    // stage A (32 rows x 512 f32 -> bf16 frag order), coalesced float4
    #pragma unroll
    for (int i=0;i<8;++i){
        const int idx = t + (i<<9);            // 0..4095 float4 units
        const int fr = idx >> 7, fc4 = idx & 127;
        float4 xv = *(const float4*)&x[(size_t)(rowbase+fr)*512 + fc4*4];
        uint2 pkv; pkv.x = pk2(xv.x,xv.y); pkv.y = pk2(xv.z,xv.w);
        const int s = fc4 >> 3, qd = (fc4 >> 1) & 3, j0 = (fc4 & 1)*4;
        *(uint2*)&Asf[(fr>>4)*8192 + s*512 + (qd*16 + (fr&15))*8 + j0] = pkv;
    }
    f4 acc[10];
    #pragma unroll
    for (int i=0;i<10;++i) acc[i] = (f4){0.f,0.f,0.f,0.f};
    LKBAR();                        // A-frags visible; vm prefetch NOT drained

    #pragma unroll
    for (int s=0;s<16;++s){
        // top: wave's own chunk-s loads done; chunk s+1 stays in flight
        if (s+1 < 16){ WAITV(5); } else { WAITV(0); }
        SBAR(); CFENCE();
        if (s+2 < 16){              // overwrite Bs[(s-1)%3]; barrier above covers
            #pragma unroll
            for (int i=0;i<5;++i)
                glds16((const char*)wqkv_p + (size_t)(s+2)*40960 + (size_t)w*5120 + i*1024 + lane*16,
                       (char*)Bs[(s+2)%3] + w*5120 + i*1024);
        }
        const u16* Bcur = Bs[s%3];
        bh8 a = *(const bh8*)&Asf[rg*8192 + s*512 + (quad*16+c)*8];
        __builtin_amdgcn_s_setprio(1);
        #pragma unroll
        for (int nt2=0;nt2<10;++nt2){
            bh8 bb = *(const bh8*)&Bcur[((cg*10+nt2)*4 + quad)*128 + c*8];
            acc[nt2] = MFMA16(a, bb, acc[nt2]);
        }
        __builtin_amdgcn_s_setprio(0);
    }

    // epilogue: Q/K -> frag panels (+bias); V -> B-operand frag layout (no bias)
    const int rt = (blockIdx.x<<1) + rg;
    const int bd = rowbase >> 8;
    const int kloc = (rowbase & 255) + rg*16 + quad*4;     // + reg
    const int sv = kloc >> 5, kq = (kloc >> 3) & 3, jk0 = kloc & 7;  // reg-invariant
    #pragma unroll
    for (int nt2=0;nt2<10;++nt2){
        const int colb = cg*160 + nt2*16;
        if (colb < 128){
            const bool isK = (colb >= 64);
            const int r = colb - (isK ? 64 : 0) + c;
            const float bias = isK ? bk[r] : bq[r];
            u16* dstb = (isK ? Kb : Qb) + ((size_t)(rt*2 + (r>>5))*4 + ((r>>3)&3))*128 + (r&7);
            #pragma unroll
            for (int reg=0;reg<4;++reg)
                dstb[(quad*4+reg)*8] = bf16r(acc[nt2][reg] + bias);
        } else {
            const int ntv = (colb - 128) >> 4;             // channel group; cv = c
            u16* dstv = Vb + (size_t)bd*131072 + (size_t)sv*16384
                           + (size_t)((ntv*4+kq)*128 + c*8 + jk0);
            ushort4 o;
            o.x = bf16r(acc[nt2][0]); o.y = bf16r(acc[nt2][1]);
            o.z = bf16r(acc[nt2][2]); o.w = bf16r(acc[nt2][3]);
            *(ushort4*)dstv = o;
        }
    }
}

// ---------------- K234: scores+softmax-fold, a2@V, LN, y1@wm, LN ----------------
// 512 blocks x 256 thr (4 waves = 4 cg), 16 rows/block, LDS = 80 KB -> 2 blk/CU.
__global__ __launch_bounds__(256) void k234(
    const u16* __restrict__ Qb, const u16* __restrict__ Kb, const u16* __restrict__ Vb,
    const u16* __restrict__ wm_p,
    const float* __restrict__ x, const float* __restrict__ bv,
    const float* __restrict__ g1, const float* __restrict__ b1,
    const float* __restrict__ bm, const float* __restrict__ g2, const float* __restrict__ b2,
    float* __restrict__ out)
{
    __shared__ u16 Bs[2][16384];    // 64 KB ring (32 KB per buffer)
    __shared__ u16 U[8192];         // 16 KB union:
                                    //  qsf  = U[0..1023]   (prologue only)
                                    //  a2f  = U[0..4095]   (softmax -> phase B)
                                    //  y1f  = U[0..8191]   (epilogue1 -> phase D)
                                    //  red  = bytes 8192..8703 (phase-dead slice)
    u16* const qsf = U;
    u16* const a2f = U;
    u16* const y1f = U;
    float* const redA = (float*)&U[4096];   // [4][16]
    float* const redB = redA + 64;          // [4][16]
    const int t = threadIdx.x, w = t>>6, lane = t&63, quad = (lane>>4)&3, c = lane&15;
    const int cg = w;                                       // 4 waves, 1 rg
    const int bd = blockIdx.x & 31, ftile = blockIdx.x >> 5; // bid%8==bd%8 -> same XCD per bd
    const int b = bd >> 3;
    const int rowbase = (bd<<8) + (ftile<<4);
    const int rt = rowbase >> 4;
    const char* Kbase = (const char*)Kb + (size_t)b*262144;
    const char* Vbase = (const char*)Vb + (size_t)bd*262144;

    // ---- prologue: Q frags (2 KB) + key-chunk 0 (32 KB)
    if (w < 2) glds16((const char*)Qb + (size_t)rt*2048 + w*1024 + lane*16,
                      (char*)qsf + w*1024);
    #pragma unroll
    for (int i=0;i<8;++i)
        glds16(Kbase + (size_t)(w*8+i)*1024 + lane*16, (char*)Bs[0] + (w*8+i)*1024);
    WAITV(8);                       // Q loads (oldest) done; chunk0 in flight
    SBAR(); CFENCE();
    bh8 aq0 = *(const bh8*)&qsf[(quad*16+c)*8];
    bh8 aq1 = *(const bh8*)&qsf[512 + (quad*16+c)*8];

    float lp[4] = {0.f,0.f,0.f,0.f};
    float a2r[4][4] = {};
    // ---- Phase A: 8 chunks x 256 keys; exp + g-fold (chunk cc == depth g)
    #pragma unroll
    for (int cc=0; cc<8; ++cc){
        WAITV(0);                   // own chunk-cc loads done
        SBAR(); CFENCE();           // => whole chunk cc complete for all waves
        if (cc+1 < 8){              // overwrite Bs[(cc+1)&1] (read at cc-1)
            #pragma unroll
            for (int i=0;i<8;++i)
                glds16(Kbase + (size_t)(cc+1)*32768 + (size_t)(w*8+i)*1024 + lane*16,
                       (char*)Bs[(cc+1)&1] + (w*8+i)*1024);
        }
        const u16* Bcur = Bs[cc&1];
        __builtin_amdgcn_s_setprio(1);
        f4 sa[4];
        #pragma unroll
        for (int kt=0;kt<4;++kt){
            sa[kt] = (f4){0.f,0.f,0.f,0.f};
            bh8 b0 = *(const bh8*)&Bcur[(cg*4+kt)*1024 + (quad*16+c)*8];
            bh8 bv1= *(const bh8*)&Bcur[(cg*4+kt)*1024 + 512 + (quad*16+c)*8];
            sa[kt] = MFMA16(aq0, b0, sa[kt]);
            sa[kt] = MFMA16(aq1, bv1, sa[kt]);
        }
        __builtin_amdgcn_s_setprio(0);
        #pragma unroll
        for (int kt=0;kt<4;++kt)
            #pragma unroll
            for (int reg=0;reg<4;++reg){
                float e = __expf(sa[kt][reg]);
                lp[reg] += e;
                a2r[reg][kt] += e;
            }
    }
    // issue V chunk0 -> Bs[0] (last read cc=6; top-of-cc=7 barrier covered it)
    #pragma unroll
    for (int i=0;i<8;++i)
        glds16(Vbase + (size_t)(w*8+i)*1024 + lane*16, (char*)Bs[0] + (w*8+i)*1024);
    // softmax denominator: reduce over c lanes, then across 4 cg waves
    #pragma unroll
    for (int reg=0;reg<4;++reg){
        float v = lp[reg];
        v += __shfl_xor(v,1,64); v += __shfl_xor(v,2,64);
        v += __shfl_xor(v,4,64); v += __shfl_xor(v,8,64);
        lp[reg] = v;
    }
    if (c==0){
        #pragma unroll
        for (int reg=0;reg<4;++reg) redA[cg*16 + quad*4+reg] = lp[reg];
    }
    LKBAR();
    // issue V chunk1 -> Bs[1] (last read cc=7; LKBAR above covered it)
    #pragma unroll
    for (int i=0;i<8;++i)
        glds16(Vbase + 32768 + (size_t)(w*8+i)*1024 + lane*16, (char*)Bs[1] + (w*8+i)*1024);
    float fac[4];
    #pragma unroll
    for (int reg=0;reg<4;++reg){
        const int q = quad*4+reg;
        fac[reg] = 1.f/(redA[q]+redA[16+q]+redA[32+q]+redA[48+q]);
    }
    #pragma unroll
    for (int reg=0;reg<4;++reg)
        #pragma unroll
        for (int kt=0;kt<4;++kt){
            const int jp = cg*64 + kt*16 + c;
            a2f[(jp>>5)*512 + (((jp>>3)&3)*16 + quad*4+reg)*8 + (jp&7)]
                = bf16r(a2r[reg][kt]*fac[reg]);
        }
    LKBAR();                        // a2f visible; V prefetch still in flight

    // ---- Phase B: attn = a2 @ V  (K=256, 8 steps)
    f4 cacc[8];
    #pragma unroll
    for (int i=0;i<8;++i) cacc[i] = (f4){0.f,0.f,0.f,0.f};
    #pragma unroll
    for (int s8=0;s8<8;++s8){
        if (s8==0){ WAITV(8); } else { WAITV(0); }
        SBAR(); CFENCE();
        if (s8>=1 && s8+1<8){
            #pragma unroll
            for (int i=0;i<8;++i)
                glds16(Vbase + (size_t)(s8+1)*32768 + (size_t)(w*8+i)*1024 + lane*16,
                       (char*)Bs[(s8+1)&1] + (w*8+i)*1024);
        }
        const u16* Bcur = Bs[s8&1];
        bh8 a = *(const bh8*)&a2f[s8*512 + (quad*16+c)*8];
        __builtin_amdgcn_s_setprio(1);
        #pragma unroll
        for (int nt2=0;nt2<8;++nt2){
            bh8 bb = *(const bh8*)&Bcur[((cg*8+nt2)*4 + quad)*128 + c*8];
            cacc[nt2] = MFMA16(a, bb, cacc[nt2]);
        }
        __builtin_amdgcn_s_setprio(0);
    }
    // issue wm chunk0 -> Bs[0] (last read s8=6; top-of-s8=7 barrier covered it)
    #pragma unroll
    for (int i=0;i<8;++i)
        glds16((const char*)wm_p + (size_t)(w*8+i)*1024 + lane*16,
               (char*)Bs[0] + (w*8+i)*1024);

    // ---- epilogue 1: + bv + x residual, LN -> y1 (f32 in cacc, bf16 frags in y1f)
    {
        float sv4[4] = {0.f,0.f,0.f,0.f}, qv2[4] = {0.f,0.f,0.f,0.f};
        #pragma unroll
        for (int nt2=0;nt2<8;++nt2){
            const int col = cg*128 + nt2*16 + c;
            const float bvv = bv[col];
            #pragma unroll
            for (int reg=0;reg<4;++reg){
                const int row = rowbase + quad*4 + reg;
                float val = cacc[nt2][reg] + bvv + x[(size_t)row*512 + col];
                cacc[nt2][reg] = val;
                sv4[reg] += val; qv2[reg] = fmaf(val,val,qv2[reg]);
            }
        }
        #pragma unroll
        for (int reg=0;reg<4;++reg){
            float s1=sv4[reg], s2=qv2[reg];
            s1 += __shfl_xor(s1,1,64); s2 += __shfl_xor(s2,1,64);
            s1 += __shfl_xor(s1,2,64); s2 += __shfl_xor(s2,2,64);
            s1 += __shfl_xor(s1,4,64); s2 += __shfl_xor(s2,4,64);
            s1 += __shfl_xor(s1,8,64); s2 += __shfl_xor(s2,8,64);
            sv4[reg]=s1; qv2[reg]=s2;
        }
        if (c==0){
            #pragma unroll
            for (int reg=0;reg<4;++reg){ redA[cg*16+quad*4+reg]=sv4[reg]; redB[cg*16+quad*4+reg]=qv2[reg]; }
        }
        LKBAR();
        // issue wm chunk1 -> Bs[1] (last read s8=7; LKBAR above covered it)
        #pragma unroll
        for (int i=0;i<8;++i)
            glds16((const char*)wm_p + 32768 + (size_t)(w*8+i)*1024 + lane*16,
                   (char*)Bs[1] + (w*8+i)*1024);
        float mean[4], rstd[4];
        #pragma unroll
        for (int reg=0;reg<4;++reg){
            const int q = quad*4+reg;
            const float S  = redA[q]+redA[16+q]+redA[32+q]+redA[48+q];
            const float Q2 = redB[q]+redB[16+q]+redB[32+q]+redB[48+q];
            const float m = S*(1.f/512.f);
            mean[reg]=m; rstd[reg]=rsqrtf(Q2*(1.f/512.f) - m*m + LN_EPS);
        }
        SBAR(); CFENCE();           // all red reads done before y1f overwrites red bytes
        #pragma unroll
        for (int nt2=0;nt2<8;++nt2){
            const int col = cg*128 + nt2*16 + c;
            const float gg = g1[col], bb1 = b1[col];
            #pragma unroll
            for (int reg=0;reg<4;++reg){
                float y = (cacc[nt2][reg]-mean[reg])*rstd[reg]*gg + bb1;
                cacc[nt2][reg] = y;
                y1f[(col>>5)*512 + (((col>>3)&3)*16 + quad*4+reg)*8 + (col&7)] = bf16r(y);
            }
        }
        LKBAR();                    // y1f visible; wm prefetch still in flight
    }

    // ---- Phase D: mlp = y1 @ wm (K=512, 16 steps)
    f4 dacc[8];
    #pragma unroll
    for (int i=0;i<8;++i) dacc[i] = (f4){0.f,0.f,0.f,0.f};
    #pragma unroll
    for (int s=0;s<16;++s){
        if (s==0){ WAITV(8); } else { WAITV(0); }
        SBAR(); CFENCE();
        if (s>=1 && s+1<16){
            #pragma unroll
            for (int i=0;i<8;++i)
                glds16((const char*)wm_p + (size_t)(s+1)*32768 + (size_t)(w*8+i)*1024 + lane*16,
                       (char*)Bs[(s+1)&1] + (w*8+i)*1024);
        }
        const u16* Bcur = Bs[s&1];
        bh8 a = *(const bh8*)&y1f[s*512 + (quad*16+c)*8];
        __builtin_amdgcn_s_setprio(1);
        #pragma unroll
        for (int nt2=0;nt2<8;++nt2){
            bh8 bb = *(const bh8*)&Bcur[((cg*8+nt2)*4 + quad)*128 + c*8];
            dacc[nt2] = MFMA16(a, bb, dacc[nt2]);
        }
        __builtin_amdgcn_s_setprio(0);
    }

    // ---- epilogue 2: relu(+bm) + y1 residual, LN -> out
    // red bytes = y1f step-8 frags: last read at phase-D step 8, long past.
    {
        float sv4[4] = {0.f,0.f,0.f,0.f}, qv2[4] = {0.f,0.f,0.f,0.f};
        #pragma unroll
        for (int nt2=0;nt2<8;++nt2){
            const int col = cg*128 + nt2*16 + c;
            const float bmv = bm[col];
            #pragma unroll
            for (int reg=0;reg<4;++reg){
                float hh = fmaxf(dacc[nt2][reg]+bmv, 0.f) + cacc[nt2][reg];
                dacc[nt2][reg] = hh;
                sv4[reg] += hh; qv2[reg] = fmaf(hh,hh,qv2[reg]);
            }
        }
        #pragma unroll
        for (int reg=0;reg<4;++reg){
            float s1=sv4[reg], s2=qv2[reg];
            s1 += __shfl_xor(s1,1,64); s2 += __shfl_xor(s2,1,64);
            s1 += __shfl_xor(s1,2,64); s2 += __shfl_xor(s2,2,64);
            s1 += __shfl_xor(s1,4,64); s2 += __shfl_xor(s2,4,64);
            s1 += __shfl_xor(s1,8,64); s2 += __shfl_xor(s2,8,64);
            sv4[reg]=s1; qv2[reg]=s2;
        }
        if (c==0){
            #pragma unroll
            for (int reg=0;reg<4;++reg){ redA[cg*16+quad*4+reg]=sv4[reg]; redB[cg*16+quad*4+reg]=qv2[reg]; }
        }
        LKBAR();
        float mean[4], rstd[4];
        #pragma unroll
        for (int reg=0;reg<4;++reg){
            const int q = quad*4+reg;
            const float S  = redA[q]+redA[16+q]+redA[32+q]+redA[48+q];
            const float Q2 = redB[q]+redB[16+q]+redB[32+q]+redB[48+q];
            const float m = S*(1.f/512.f);
            mean[reg]=m; rstd[reg]=rsqrtf(Q2*(1.f/512.f) - m*m + LN_EPS);
        }
        #pragma unroll
        for (int nt2=0;nt2<8;++nt2){
            const int col = cg*128 + nt2*16 + c;
            const float gg = g2[col], bb2 = b2[col];
            #pragma unroll
            for (int reg=0;reg<4;++reg){
                const int row = rowbase + quad*4 + reg;
                out[(size_t)row*512 + col] = (dacc[nt2][reg]-mean[reg])*rstd[reg]*gg + bb2;
            }
        }
    }
}

extern "C" void kernel_launch(void* const* d_in, const int* in_sizes, int n_in,
                              void* d_out, int out_size, void* d_ws, size_t ws_size,
                              hipStream_t stream) {
    (void)in_sizes; (void)n_in; (void)out_size; (void)ws_size;
    const float* x  = (const float*)d_in[0];
    const float* wq = (const float*)d_in[1];
    const float* bq = (const float*)d_in[2];
    const float* wk = (const float*)d_in[3];
    const float* bk = (const float*)d_in[4];
    const float* wv = (const float*)d_in[5];
    const float* bv = (const float*)d_in[6];
    const float* wm = (const float*)d_in[7];
    const float* bm = (const float*)d_in[8];
    const float* g1 = (const float*)d_in[9];
    const float* b1 = (const float*)d_in[10];
    const float* g2 = (const float*)d_in[11];
    const float* b2 = (const float*)d_in[12];

    // ws layout (11.67 MB): bf16 frag panels
    u16* wqkv_p = (u16*)d_ws;                  // 640 KB (16 s x 40 nt x 512)
    u16* wm_p   = wqkv_p + 327680;             // 512 KB
    u16* Qb     = wm_p   + 262144;             // 1 MB  (512 rt x 2048 B)
    u16* Kb     = Qb     + 524288;             // 1 MB
    u16* Vb     = Kb     + 524288;             // 8 MB  (32 bd x 8 s x 16384)
    float* outp = (float*)d_out;

    k0_prep<<<64, 256, 0, stream>>>(wq, wk, wv, wm, wqkv_p, wm_p);
    k1_qkv <<<256, 512, 0, stream>>>(x, bq, bk, wqkv_p, Qb, Kb, Vb);
    k234   <<<512, 256, 0, stream>>>(Qb, Kb, Vb, wm_p, x, bv, g1, b1, bm, g2, b2, outp);
}

// Round 5
// 127.233 us; speedup vs baseline: 1.2748x; 1.2748x over previous
//
#include <hip/hip_runtime.h>
#include <cstdint>

// B,D,H,W,C = 4,8,16,16,512; R=64; F=256; rows=8192; keys/batch=2048.
// v6: barrier-free K-loops via register-direct B operands.
//   All B panels (Kb/Vb/wm_p/wqkv_p) are stored in MFMA fragment order, so
//   each wave loads its B-frags straight to VGPRs (1 KB coalesced per frag).
//   Waves are re-split so B-frags are wave-unique: 8 waves x 64 cols, each
//   wave computes 2 row-tiles (32 rows/block). Aggregate L2 traffic unchanged
//   (32 KB/step/CU) but NO LDS staging, NO in-loop barriers: waves free-run
//   and cover each other's latency (m114). 1-step register prefetch per loop.
//   LDS: 32 KB A-frag union (a2f/y1f) + 2 KB LN scratch. 5 barriers total.
#define LN_EPS 1e-3f
using u16 = unsigned short;
using u32 = unsigned int;
typedef __attribute__((ext_vector_type(8))) short bh8;   // 8 bf16
typedef __attribute__((ext_vector_type(4))) float f4;    // 4 f32 acc
#define MFMA16(A,B,C) __builtin_amdgcn_mfma_f32_16x16x32_bf16((A),(B),(C),0,0,0)
#define LKBAR() do{ asm volatile("s_waitcnt lgkmcnt(0)" ::: "memory"); \
                    __builtin_amdgcn_s_barrier(); asm volatile("" ::: "memory"); }while(0)

__device__ __forceinline__ u16 bf16r(float f){
    union{float f;u32 u;} c; c.f=f;
    return (u16)((c.u + 0x7fffu + ((c.u>>16)&1u))>>16);
}
__device__ __forceinline__ u32 pk2(float a, float b){
    return (u32)bf16r(a) | ((u32)bf16r(b)<<16);
}

// ---------------- K0: pack weights -> bf16 frag-ordered B panels ----------------
__global__ __launch_bounds__(256) void k0_prep(
    const float* __restrict__ wq, const float* __restrict__ wk,
    const float* __restrict__ wv, const float* __restrict__ wm,
    u16* __restrict__ wqkv_p, u16* __restrict__ wm_p)
{
    const int t = threadIdx.x;
    const int c = t & 15, qn = t >> 4;
    const int quad = qn & 3, ntl = qn >> 2;   // ntl 0..3
    const int blk = blockIdx.x;
    if (blk < 32){
        const int s = blk >> 1, hh = blk & 1;
        const int krow = s*32 + quad*8;
        u16* dst = wqkv_p + (size_t)s*20480;
        #pragma unroll
        for (int i=0;i<5;++i){
            const int nt = hh*20 + i*4 + ntl;
            const int n = nt*16 + c;
            const float* src; int ldw;
            if (n < 64){ src = wq + (size_t)krow*64 + n; ldw = 64; }
            else if (n < 128){ src = wk + (size_t)krow*64 + (n-64); ldw = 64; }
            else { src = wv + (size_t)krow*512 + (n-128); ldw = 512; }
            float v[8];
            #pragma unroll
            for (int j=0;j<8;++j) v[j] = src[(size_t)j*ldw];
            uint4 o; o.x=pk2(v[0],v[1]); o.y=pk2(v[2],v[3]); o.z=pk2(v[4],v[5]); o.w=pk2(v[6],v[7]);
            *(uint4*)&dst[((nt*4+quad)*16 + c)*8] = o;
        }
    } else {
        const int bb = blk - 32;
        const int s = bb >> 1, hh = bb & 1;
        const int krow = s*32 + quad*8;
        u16* dst = wm_p + (size_t)s*16384;
        #pragma unroll
        for (int i=0;i<4;++i){
            const int nt = hh*16 + i*4 + ntl;
            const int n = nt*16 + c;
            const float* src = wm + (size_t)krow*512 + n;
            float v[8];
            #pragma unroll
            for (int j=0;j<8;++j) v[j] = src[(size_t)j*512];
            uint4 o; o.x=pk2(v[0],v[1]); o.y=pk2(v[2],v[3]); o.z=pk2(v[4],v[5]); o.w=pk2(v[6],v[7]);
            *(uint4*)&dst[((nt*4+quad)*16 + c)*8] = o;
        }
    }
}

// ---------------- K1: fused QKV projection, reg-direct B, no in-loop barriers --
// 256 blocks x 512 thr; 32 rows/block; 8 waves x 80 cols x 2 row-tiles.
__global__ __launch_bounds__(512) void k1_qkv(
    const float* __restrict__ x, const float* __restrict__ bq, const float* __restrict__ bk,
    const u16* __restrict__ wqkv_p,
    u16* __restrict__ Qb, u16* __restrict__ Kb, u16* __restrict__ Vb)
{
    __shared__ u16 Asf[16384];      // 32 KB: 2 rt x 16 s x 512 (A frags)
    const int t = threadIdx.x, w = t>>6, lane = t&63, quad = (lane>>4)&3, c = lane&15;
    const int rowbase = blockIdx.x << 5;

    // stage A (32 rows x 512 f32 -> bf16 frag order), coalesced float4
    #pragma unroll
    for (int i=0;i<8;++i){
        const int idx = t + (i<<9);            // 0..4095 float4 units
        const int fr = idx >> 7, fc4 = idx & 127;
        float4 xv = *(const float4*)&x[(size_t)(rowbase+fr)*512 + fc4*4];
        uint2 pkv; pkv.x = pk2(xv.x,xv.y); pkv.y = pk2(xv.z,xv.w);
        const int s = fc4 >> 3, qd = (fc4 >> 1) & 3, j0 = (fc4 & 1)*4;
        *(uint2*)&Asf[(fr>>4)*8192 + s*512 + (qd*16 + (fr&15))*8 + j0] = pkv;
    }
    f4 acc[2][5];
    #pragma unroll
    for (int rt=0;rt<2;++rt)
        #pragma unroll
        for (int i=0;i<5;++i) acc[rt][i] = (f4){0.f,0.f,0.f,0.f};
    // prefetch B s=0 (overlaps A-stage drain)
    bh8 bw[5];
    #pragma unroll
    for (int nt2=0;nt2<5;++nt2)
        bw[nt2] = *(const bh8*)&wqkv_p[(size_t)((w*5+nt2)*4 + quad)*128 + c*8];
    __syncthreads();

    #pragma unroll
    for (int s=0;s<16;++s){
        bh8 bn[5];
        if (s+1 < 16){
            #pragma unroll
            for (int nt2=0;nt2<5;++nt2)
                bn[nt2] = *(const bh8*)&wqkv_p[(size_t)(s+1)*20480 + ((w*5+nt2)*4 + quad)*128 + c*8];
        }
        bh8 a[2];
        #pragma unroll
        for (int rt=0;rt<2;++rt)
            a[rt] = *(const bh8*)&Asf[rt*8192 + s*512 + (quad*16+c)*8];
        #pragma unroll
        for (int rt=0;rt<2;++rt)
            #pragma unroll
            for (int nt2=0;nt2<5;++nt2)
                acc[rt][nt2] = MFMA16(a[rt], bw[nt2], acc[rt][nt2]);
        if (s+1 < 16){
            #pragma unroll
            for (int nt2=0;nt2<5;++nt2) bw[nt2] = bn[nt2];
        }
    }

    // epilogue: Q/K -> frag panels (+bias); V -> B-operand frag layout (no bias)
    const int bd = rowbase >> 8;
    #pragma unroll
    for (int rt=0;rt<2;++rt){
        const int rtg = (blockIdx.x<<1) + rt;
        const int kloc = (rowbase & 255) + rt*16 + quad*4;     // + reg
        const int sv = kloc >> 5, kq = (kloc >> 3) & 3, jk0 = kloc & 7;
        #pragma unroll
        for (int nt2=0;nt2<5;++nt2){
            const int colb = w*80 + nt2*16;
            if (colb < 128){
                const bool isK = (colb >= 64);
                const int r = colb - (isK ? 64 : 0) + c;
                const float bias = isK ? bk[r] : bq[r];
                u16* dstb = (isK ? Kb : Qb) + ((size_t)(rtg*2 + (r>>5))*4 + ((r>>3)&3))*128 + (r&7);
                #pragma unroll
                for (int reg=0;reg<4;++reg)
                    dstb[(quad*4+reg)*8] = bf16r(acc[rt][nt2][reg] + bias);
            } else {
                const int ntv = (colb - 128) >> 4;             // channel group; col-in-tile = c
                u16* dstv = Vb + (size_t)bd*131072 + (size_t)sv*16384
                               + (size_t)((ntv*4+kq)*128 + c*8 + jk0);
                ushort4 o;
                o.x = bf16r(acc[rt][nt2][0]); o.y = bf16r(acc[rt][nt2][1]);
                o.z = bf16r(acc[rt][nt2][2]); o.w = bf16r(acc[rt][nt2][3]);
                *(ushort4*)dstv = o;
            }
        }
    }
}

// ---------------- K234: attn + LN + MLP + LN, reg-direct B, 5 barriers total --
// 256 blocks x 512 thr; 32 rows/block; 8 waves x 64 cols (32 keys-h) x 2 rt.
__global__ __launch_bounds__(512) void k234(
    const u16* __restrict__ Qb, const u16* __restrict__ Kb, const u16* __restrict__ Vb,
    const u16* __restrict__ wm_p,
    const float* __restrict__ x, const float* __restrict__ bv,
    const float* __restrict__ g1, const float* __restrict__ b1,
    const float* __restrict__ bm, const float* __restrict__ g2, const float* __restrict__ b2,
    float* __restrict__ out)
{
    __shared__ u16 U[16384];        // 32 KB union: a2f = U[0..8191] (2rt x 8s x 512)
                                    //              y1f = U[0..16383] (2rt x 16s x 512)
    __shared__ float redA[256], redB[256];   // [w(8)][rt(2)][q(16)]
    const int t = threadIdx.x, w = t>>6, lane = t&63, quad = (lane>>4)&3, c = lane&15;
    const int bd = blockIdx.x & 31, ftile = blockIdx.x >> 5;   // XCD-aligned decode
    const int b = bd >> 3;
    const int rowbase = (bd<<8) + (ftile<<5);
    const int rt00 = rowbase >> 4;
    const u16* Kp = Kb + (size_t)b*131072;
    const u16* Vp = Vb + (size_t)bd*131072;

    // ---- Q frags, reg-direct (broadcast across waves; 4 KB/wave)
    bh8 aq[2][2];
    #pragma unroll
    for (int rt=0;rt<2;++rt)
        #pragma unroll
        for (int kk=0;kk<2;++kk)
            aq[rt][kk] = *(const bh8*)&Qb[(size_t)(rt00+rt)*1024 + kk*512 + (quad*16+c)*8];

    float lp[2][4] = {};
    float a2r[2][2][4] = {};
    // ---- Phase A: 8 depth-chunks x 256 keys; wave owns 32 h-cols (2 kt tiles)
    bh8 bk0[2][2];
    #pragma unroll
    for (int kt=0;kt<2;++kt)
        #pragma unroll
        for (int kk=0;kk<2;++kk)
            bk0[kt][kk] = *(const bh8*)&Kp[(size_t)(w*2+kt)*1024 + kk*512 + (quad*16+c)*8];
    #pragma unroll
    for (int cc=0; cc<8; ++cc){
        bh8 bn[2][2];
        if (cc+1 < 8){
            #pragma unroll
            for (int kt=0;kt<2;++kt)
                #pragma unroll
                for (int kk=0;kk<2;++kk)
                    bn[kt][kk] = *(const bh8*)&Kp[(size_t)((cc+1)*16 + w*2+kt)*1024 + kk*512 + (quad*16+c)*8];
        }
        #pragma unroll
        for (int rt=0;rt<2;++rt)
            #pragma unroll
            for (int kt=0;kt<2;++kt){
                f4 sa = (f4){0.f,0.f,0.f,0.f};
                sa = MFMA16(aq[rt][0], bk0[kt][0], sa);
                sa = MFMA16(aq[rt][1], bk0[kt][1], sa);
                #pragma unroll
                for (int reg=0;reg<4;++reg){
                    float e = __expf(sa[reg]);
                    lp[rt][reg] += e;
                    a2r[rt][kt][reg] += e;
                }
            }
        if (cc+1 < 8){
            #pragma unroll
            for (int kt=0;kt<2;++kt)
                #pragma unroll
                for (int kk=0;kk<2;++kk) bk0[kt][kk] = bn[kt][kk];
        }
    }
    // prefetch V s=0 (independent of softmax)
    bh8 bv8[4];
    #pragma unroll
    for (int nt2=0;nt2<4;++nt2)
        bv8[nt2] = *(const bh8*)&Vp[(size_t)((w*4+nt2)*4 + quad)*128 + c*8];
    // softmax denominator: shfl over c lanes, then across 8 waves via LDS
    #pragma unroll
    for (int rt=0;rt<2;++rt)
        #pragma unroll
        for (int reg=0;reg<4;++reg){
            float v = lp[rt][reg];
            v += __shfl_xor(v,1,64); v += __shfl_xor(v,2,64);
            v += __shfl_xor(v,4,64); v += __shfl_xor(v,8,64);
            lp[rt][reg] = v;
        }
    if (c==0){
        #pragma unroll
        for (int rt=0;rt<2;++rt)
            #pragma unroll
            for (int reg=0;reg<4;++reg) redA[w*32 + rt*16 + quad*4+reg] = lp[rt][reg];
    }
    LKBAR();
    float fac[2][4];
    #pragma unroll
    for (int rt=0;rt<2;++rt)
        #pragma unroll
        for (int reg=0;reg<4;++reg){
            const int q = rt*16 + quad*4 + reg;
            float s = 0.f;
            #pragma unroll
            for (int ww=0;ww<8;++ww) s += redA[ww*32 + q];
            fac[rt][reg] = 1.f/s;
        }
    #pragma unroll
    for (int rt=0;rt<2;++rt)
        #pragma unroll
        for (int kt=0;kt<2;++kt)
            #pragma unroll
            for (int reg=0;reg<4;++reg){
                const int jp = w*32 + kt*16 + c;
                U[rt*4096 + (jp>>5)*512 + (((jp>>3)&3)*16 + quad*4+reg)*8 + (jp&7)]
                    = bf16r(a2r[rt][kt][reg]*fac[rt][reg]);
            }
    LKBAR();                        // a2f visible; V prefetch (regs) untouched

    // ---- Phase B: attn = a2 @ V  (K=256, 8 steps, barrier-free)
    f4 cacc[2][4];
    #pragma unroll
    for (int rt=0;rt<2;++rt)
        #pragma unroll
        for (int i=0;i<4;++i) cacc[rt][i] = (f4){0.f,0.f,0.f,0.f};
    #pragma unroll
    for (int s8=0;s8<8;++s8){
        bh8 bn[4];
        if (s8+1 < 8){
            #pragma unroll
            for (int nt2=0;nt2<4;++nt2)
                bn[nt2] = *(const bh8*)&Vp[(size_t)(s8+1)*16384 + ((w*4+nt2)*4 + quad)*128 + c*8];
        }
        bh8 a[2];
        #pragma unroll
        for (int rt=0;rt<2;++rt)
            a[rt] = *(const bh8*)&U[rt*4096 + s8*512 + (quad*16+c)*8];
        #pragma unroll
        for (int rt=0;rt<2;++rt)
            #pragma unroll
            for (int nt2=0;nt2<4;++nt2)
                cacc[rt][nt2] = MFMA16(a[rt], bv8[nt2], cacc[rt][nt2]);
        if (s8+1 < 8){
            #pragma unroll
            for (int nt2=0;nt2<4;++nt2) bv8[nt2] = bn[nt2];
        }
    }
    // prefetch wm s=0
    bh8 bm8[4];
    #pragma unroll
    for (int nt2=0;nt2<4;++nt2)
        bm8[nt2] = *(const bh8*)&wm_p[(size_t)((w*4+nt2)*4 + quad)*128 + c*8];

    // ---- epilogue 1: + bv + x residual, LN -> y1 (f32 in cacc, bf16 frags in y1f)
    float mean1[2][4], rstd1[2][4];
    {
        float sv4[2][4] = {}, qv2[2][4] = {};
        #pragma unroll
        for (int rt=0;rt<2;++rt)
            #pragma unroll
            for (int nt2=0;nt2<4;++nt2){
                const int col = w*64 + nt2*16 + c;
                const float bvv = bv[col];
                #pragma unroll
                for (int reg=0;reg<4;++reg){
                    const int row = rowbase + rt*16 + quad*4 + reg;
                    float val = cacc[rt][nt2][reg] + bvv + x[(size_t)row*512 + col];
                    cacc[rt][nt2][reg] = val;
                    sv4[rt][reg] += val; qv2[rt][reg] = fmaf(val,val,qv2[rt][reg]);
                }
            }
        #pragma unroll
        for (int rt=0;rt<2;++rt)
            #pragma unroll
            for (int reg=0;reg<4;++reg){
                float s1=sv4[rt][reg], s2=qv2[rt][reg];
                s1 += __shfl_xor(s1,1,64); s2 += __shfl_xor(s2,1,64);
                s1 += __shfl_xor(s1,2,64); s2 += __shfl_xor(s2,2,64);
                s1 += __shfl_xor(s1,4,64); s2 += __shfl_xor(s2,4,64);
                s1 += __shfl_xor(s1,8,64); s2 += __shfl_xor(s2,8,64);
                sv4[rt][reg]=s1; qv2[rt][reg]=s2;
            }
        if (c==0){
            #pragma unroll
            for (int rt=0;rt<2;++rt)
                #pragma unroll
                for (int reg=0;reg<4;++reg){
                    redA[w*32 + rt*16 + quad*4+reg]=sv4[rt][reg];
                    redB[w*32 + rt*16 + quad*4+reg]=qv2[rt][reg];
                }
        }
        LKBAR();                    // all waves past phase B -> a2f dead, y1f may alias
        #pragma unroll
        for (int rt=0;rt<2;++rt)
            #pragma unroll
            for (int reg=0;reg<4;++reg){
                const int q = rt*16 + quad*4 + reg;
                float S=0.f, Q2=0.f;
                #pragma unroll
                for (int ww=0;ww<8;++ww){ S += redA[ww*32+q]; Q2 += redB[ww*32+q]; }
                const float m = S*(1.f/512.f);
                mean1[rt][reg]=m; rstd1[rt][reg]=rsqrtf(Q2*(1.f/512.f) - m*m + LN_EPS);
            }
        #pragma unroll
        for (int rt=0;rt<2;++rt)
            #pragma unroll
            for (int nt2=0;nt2<4;++nt2){
                const int col = w*64 + nt2*16 + c;
                const float gg = g1[col], bb1 = b1[col];
                #pragma unroll
                for (int reg=0;reg<4;++reg){
                    float y = (cacc[rt][nt2][reg]-mean1[rt][reg])*rstd1[rt][reg]*gg + bb1;
                    cacc[rt][nt2][reg] = y;
                    U[rt*8192 + (col>>5)*512 + (((col>>3)&3)*16 + quad*4+reg)*8 + (col&7)] = bf16r(y);
                }
            }
        LKBAR();                    // y1f visible; wm prefetch (regs) untouched
    }

    // ---- Phase D: mlp = y1 @ wm (K=512, 16 steps, barrier-free)
    f4 dacc[2][4];
    #pragma unroll
    for (int rt=0;rt<2;++rt)
        #pragma unroll
        for (int i=0;i<4;++i) dacc[rt][i] = (f4){0.f,0.f,0.f,0.f};
    #pragma unroll
    for (int s=0;s<16;++s){
        bh8 bn[4];
        if (s+1 < 16){
            #pragma unroll
            for (int nt2=0;nt2<4;++nt2)
                bn[nt2] = *(const bh8*)&wm_p[(size_t)(s+1)*16384 + ((w*4+nt2)*4 + quad)*128 + c*8];
        }
        bh8 a[2];
        #pragma unroll
        for (int rt=0;rt<2;++rt)
            a[rt] = *(const bh8*)&U[rt*8192 + s*512 + (quad*16+c)*8];
        #pragma unroll
        for (int rt=0;rt<2;++rt)
            #pragma unroll
            for (int nt2=0;nt2<4;++nt2)
                dacc[rt][nt2] = MFMA16(a[rt], bm8[nt2], dacc[rt][nt2]);
        if (s+1 < 16){
            #pragma unroll
            for (int nt2=0;nt2<4;++nt2) bm8[nt2] = bn[nt2];
        }
    }

    // ---- epilogue 2: relu(+bm) + y1 residual, LN -> out
    {
        float sv4[2][4] = {}, qv2[2][4] = {};
        #pragma unroll
        for (int rt=0;rt<2;++rt)
            #pragma unroll
            for (int nt2=0;nt2<4;++nt2){
                const int col = w*64 + nt2*16 + c;
                const float bmv = bm[col];
                #pragma unroll
                for (int reg=0;reg<4;++reg){
                    float hh = fmaxf(dacc[rt][nt2][reg]+bmv, 0.f) + cacc[rt][nt2][reg];
                    dacc[rt][nt2][reg] = hh;
                    sv4[rt][reg] += hh; qv2[rt][reg] = fmaf(hh,hh,qv2[rt][reg]);
                }
            }
        #pragma unroll
        for (int rt=0;rt<2;++rt)
            #pragma unroll
            for (int reg=0;reg<4;++reg){
                float s1=sv4[rt][reg], s2=qv2[rt][reg];
                s1 += __shfl_xor(s1,1,64); s2 += __shfl_xor(s2,1,64);
                s1 += __shfl_xor(s1,2,64); s2 += __shfl_xor(s2,2,64);
                s1 += __shfl_xor(s1,4,64); s2 += __shfl_xor(s2,4,64);
                s1 += __shfl_xor(s1,8,64); s2 += __shfl_xor(s2,8,64);
                sv4[rt][reg]=s1; qv2[rt][reg]=s2;
            }
        if (c==0){
            #pragma unroll
            for (int rt=0;rt<2;++rt)
                #pragma unroll
                for (int reg=0;reg<4;++reg){
                    redA[w*32 + rt*16 + quad*4+reg]=sv4[rt][reg];
                    redB[w*32 + rt*16 + quad*4+reg]=qv2[rt][reg];
                }
        }
        LKBAR();
        #pragma unroll
        for (int rt=0;rt<2;++rt){
            float mean[4], rstd[4];
            #pragma unroll
            for (int reg=0;reg<4;++reg){
                const int q = rt*16 + quad*4 + reg;
                float S=0.f, Q2=0.f;
                #pragma unroll
                for (int ww=0;ww<8;++ww){ S += redA[ww*32+q]; Q2 += redB[ww*32+q]; }
                const float m = S*(1.f/512.f);
                mean[reg]=m; rstd[reg]=rsqrtf(Q2*(1.f/512.f) - m*m + LN_EPS);
            }
            #pragma unroll
            for (int nt2=0;nt2<4;++nt2){
                const int col = w*64 + nt2*16 + c;
                const float gg = g2[col], bb2 = b2[col];
                #pragma unroll
                for (int reg=0;reg<4;++reg){
                    const int row = rowbase + rt*16 + quad*4 + reg;
                    out[(size_t)row*512 + col] = (dacc[rt][nt2][reg]-mean[reg])*rstd[reg]*gg + bb2;
                }
            }
        }
    }
}

extern "C" void kernel_launch(void* const* d_in, const int* in_sizes, int n_in,
                              void* d_out, int out_size, void* d_ws, size_t ws_size,
                              hipStream_t stream) {
    (void)in_sizes; (void)n_in; (void)out_size; (void)ws_size;
    const float* x  = (const float*)d_in[0];
    const float* wq = (const float*)d_in[1];
    const float* bq = (const float*)d_in[2];
    const float* wk = (const float*)d_in[3];
    const float* bk = (const float*)d_in[4];
    const float* wv = (const float*)d_in[5];
    const float* bv = (const float*)d_in[6];
    const float* wm = (const float*)d_in[7];
    const float* bm = (const float*)d_in[8];
    const float* g1 = (const float*)d_in[9];
    const float* b1 = (const float*)d_in[10];
    const float* g2 = (const float*)d_in[11];
    const float* b2 = (const float*)d_in[12];

    // ws layout (11.67 MB): bf16 frag panels
    u16* wqkv_p = (u16*)d_ws;                  // 640 KB (16 s x 40 nt x 512)
    u16* wm_p   = wqkv_p + 327680;             // 512 KB
    u16* Qb     = wm_p   + 262144;             // 1 MB  (512 rt x 2048 B)
    u16* Kb     = Qb     + 524288;             // 1 MB
    u16* Vb     = Kb     + 524288;             // 8 MB  (32 bd x 8 s x 16384 u16)
    float* outp = (float*)d_out;

    k0_prep<<<64, 256, 0, stream>>>(wq, wk, wv, wm, wqkv_p, wm_p);
    k1_qkv <<<256, 512, 0, stream>>>(x, bq, bk, wqkv_p, Qb, Kb, Vb);
    k234   <<<256, 512, 0, stream>>>(Qb, Kb, Vb, wm_p, x, bv, g1, b1, bm, g2, b2, outp);
}